// Round 2
// baseline (1076.072 us; speedup 1.0000x reference)
//
#include <hip/hip_runtime.h>
#include <hip/hip_bf16.h>

// Problem constants
constexpr int LQ  = 1024;  // L1 == L2 == 1024
constexpr int BN  = 8;
constexpr int D1N = 512;
constexpr int D2N = 1024;
constexpr int HN  = 16;
constexpr int MN  = 1024;
constexpr int DPH = 64;

typedef __attribute__((ext_vector_type(8))) short bf16x8;   // 8 bf16 in 4 VGPRs
typedef __attribute__((ext_vector_type(4))) float f32x4;

__device__ __forceinline__ unsigned short f2bf(float f) {
  unsigned u = __float_as_uint(f);
  u += 0x7FFFu + ((u >> 16) & 1u);   // RNE
  return (unsigned short)(u >> 16);
}

__device__ __forceinline__ f32x4 mfma16(bf16x8 a, bf16x8 b, f32x4 c) {
  return __builtin_amdgcn_mfma_f32_16x16x32_bf16(a, b, c, 0, 0, 0);
}

__device__ __forceinline__ bf16x8 pack8(f32x4 p0, f32x4 p1) {
  bf16x8 o;
  o[0] = (short)f2bf(p0[0]); o[1] = (short)f2bf(p0[1]);
  o[2] = (short)f2bf(p0[2]); o[3] = (short)f2bf(p0[3]);
  o[4] = (short)f2bf(p1[0]); o[5] = (short)f2bf(p1[1]);
  o[6] = (short)f2bf(p1[2]); o[7] = (short)f2bf(p1[3]);
  return o;
}

// XCD-group decode: 2048 linear blocks -> (group g in [0,128), member m16 in [0,16))
// such that the 16 members of a group are consecutive dispatches on ONE XCD
// (assumes round-robin bid%8 -> XCD, perf-only heuristic).
__device__ __forceinline__ void xcd_group(int bid, int& g, int& m16) {
  int x = bid & 7;           // XCD
  int t = bid >> 3;          // per-XCD sequence
  m16 = t & 15;              // member varies fastest within an XCD
  int gj = t >> 4;           // 0..15
  g = gj * 8 + x;            // 0..127
}

// ---------------------------------------------------------------- cvt f32->bf16
__global__ __launch_bounds__(256) void cvt_kernel(const float* __restrict__ src,
                                                  unsigned short* __restrict__ dst,
                                                  int n8) {
  int i = blockIdx.x * blockDim.x + threadIdx.x;
  if (i >= n8) return;
  const f32x4* s = (const f32x4*)src;
  f32x4 x = s[2 * i], y = s[2 * i + 1];
  ((bf16x8*)dst)[i] = pack8(x, y);
}

// ---------------------------------------------------------------- generic GEMM
// A [rows, K] bf16 row-major; W [1024, K] bf16 row-major; C = A @ W^T + bias
// MODE 0: write bf16 to [B,H,L,64]  (rows are l*8+b, cols are h*64+d)
// MODE 2: write f32 row-major [rows,1024]
template <int K, int MODE>
__global__ __launch_bounds__(256) void gemm_kernel(const unsigned short* __restrict__ A,
                                                   const unsigned short* __restrict__ W,
                                                   const float* __restrict__ bias,
                                                   void* __restrict__ outp) {
  const int wave = threadIdx.x >> 6, lane = threadIdx.x & 63;
  const int lg = lane >> 4, lm = lane & 15;
  const int rowb = blockIdx.x * 128 + (wave >> 1) * 64;
  const int colb = blockIdx.y * 128 + (wave & 1) * 64;

  f32x4 acc[4][4];
#pragma unroll
  for (int i = 0; i < 4; ++i)
#pragma unroll
    for (int j = 0; j < 4; ++j) acc[i][j] = (f32x4){0.f, 0.f, 0.f, 0.f};

  for (int kk = 0; kk < K; kk += 32) {
    bf16x8 af[4], wf[4];
#pragma unroll
    for (int i = 0; i < 4; ++i)
      af[i] = *(const bf16x8*)(A + (size_t)(rowb + i * 16 + lm) * K + kk + lg * 8);
#pragma unroll
    for (int j = 0; j < 4; ++j)
      wf[j] = *(const bf16x8*)(W + (size_t)(colb + j * 16 + lm) * K + kk + lg * 8);
#pragma unroll
    for (int i = 0; i < 4; ++i)
#pragma unroll
      for (int j = 0; j < 4; ++j) acc[i][j] = mfma16(af[i], wf[j], acc[i][j]);
  }

#pragma unroll
  for (int j = 0; j < 4; ++j) {
    int col = colb + j * 16 + lm;
    float bs = bias[col];
#pragma unroll
    for (int i = 0; i < 4; ++i) {
#pragma unroll
      for (int r = 0; r < 4; ++r) {
        int row = rowb + i * 16 + lg * 4 + r;
        float v = acc[i][j][r] + bs;
        if (MODE == 0) {
          int l = row >> 3, bb = row & 7, h = col >> 6, d = col & 63;
          ((unsigned short*)outp)[(((size_t)(bb * HN + h)) * LQ + l) * DPH + d] = f2bf(v);
        } else {
          ((float*)outp)[(size_t)row * MN + col] = v;
        }
      }
    }
  }
}

// ---------------------------------------------------------------- V transpose
// V [BH, L, 64] bf16 -> VT [BH, 64, L]
__global__ __launch_bounds__(256) void transpose_kernel(const unsigned short* __restrict__ V,
                                                        unsigned short* __restrict__ VT) {
  __shared__ unsigned short t[64][72];
  int bh = blockIdx.y, l0 = blockIdx.x * 64;
  int tid = threadIdx.x;
  int r = tid >> 2, c0 = (tid & 3) * 16;
  const unsigned short* src = V + ((size_t)bh * LQ + l0 + r) * DPH + c0;
  *(bf16x8*)&t[r][c0]     = *(const bf16x8*)(src);
  *(bf16x8*)&t[r][c0 + 8] = *(const bf16x8*)(src + 8);
  __syncthreads();
  int d = tid >> 2, lc = (tid & 3) * 16;
  bf16x8 o0, o1;
#pragma unroll
  for (int j = 0; j < 8; ++j) {
    o0[j] = (short)t[lc + j][d];
    o1[j] = (short)t[lc + 8 + j][d];
  }
  unsigned short* dst = VT + ((size_t)bh * DPH + d) * LQ + l0 + lc;
  *(bf16x8*)dst = o0;
  *(bf16x8*)(dst + 8) = o1;
}

// ---------------------------------------------------------------- col reduce
// inv_colsum[bh, k] = 1 / sum_q exp(s[bh,q,k])
// 1-D grid of 2048, XCD-grouped: group = bh, member = k-tile
__global__ __launch_bounds__(256) void col_reduce_kernel(const unsigned short* __restrict__ K1p,
                                                         const unsigned short* __restrict__ K2p,
                                                         float* __restrict__ inv_colsum) {
  int g, m16;
  xcd_group(blockIdx.x, g, m16);
  int bh = g, k0 = m16 * 64;
  int wave = threadIdx.x >> 6, lane = threadIdx.x & 63, lg = lane >> 4, lm = lane & 15;
  const unsigned short* k1 = K1p + (size_t)bh * LQ * DPH;
  const unsigned short* k2 = K2p + (size_t)bh * LQ * DPH;
  bf16x8 b0[4], b1[4];
#pragma unroll
  for (int s = 0; s < 4; ++s) {
    b0[s] = *(const bf16x8*)(k1 + (size_t)(k0 + s * 16 + lm) * 64 + lg * 8);
    b1[s] = *(const bf16x8*)(k1 + (size_t)(k0 + s * 16 + lm) * 64 + 32 + lg * 8);
  }
  float sums[4] = {0.f, 0.f, 0.f, 0.f};
  for (int q0 = wave * 16; q0 < LQ; q0 += 64) {
    bf16x8 a0 = *(const bf16x8*)(k2 + (size_t)(q0 + lm) * 64 + lg * 8);
    bf16x8 a1 = *(const bf16x8*)(k2 + (size_t)(q0 + lm) * 64 + 32 + lg * 8);
#pragma unroll
    for (int s = 0; s < 4; ++s) {
      f32x4 c = (f32x4){0.f, 0.f, 0.f, 0.f};
      c = mfma16(a0, b0[s], c);
      c = mfma16(a1, b1[s], c);
      sums[s] += __expf(c[0]) + __expf(c[1]) + __expf(c[2]) + __expf(c[3]);
    }
  }
  __shared__ float red[4][64];
#pragma unroll
  for (int s = 0; s < 4; ++s) {
    sums[s] += __shfl_xor(sums[s], 16);
    sums[s] += __shfl_xor(sums[s], 32);
    if (lg == 0) red[wave][s * 16 + lm] = sums[s];
  }
  __syncthreads();
  if (threadIdx.x < 64) {
    float t = red[0][threadIdx.x] + red[1][threadIdx.x] + red[2][threadIdx.x] + red[3][threadIdx.x];
    inv_colsum[(size_t)bh * LQ + k0 + threadIdx.x] = 1.0f / t;
  }
}

// ---------------------------------------------------------------- head reduce
// invT[b, k, q] = 1 / sum_h exp(s[b,h,q,k])   (TRANSPOSED layout, f32x4 stores)
__global__ __launch_bounds__(256) void head_reduce_kernel(const unsigned short* __restrict__ K1p,
                                                          const unsigned short* __restrict__ K2p,
                                                          float* __restrict__ invT) {
  int b = blockIdx.z, k0 = blockIdx.x * 64;
  int wave = threadIdx.x >> 6, lane = threadIdx.x & 63, lg = lane >> 4, lm = lane & 15;
  int q0 = blockIdx.y * 64 + wave * 16;
  float hs[4][4];
#pragma unroll
  for (int s = 0; s < 4; ++s)
#pragma unroll
    for (int r = 0; r < 4; ++r) hs[s][r] = 0.f;

  for (int h = 0; h < HN; ++h) {
    const unsigned short* k1 = K1p + (size_t)(b * HN + h) * LQ * DPH;
    const unsigned short* k2 = K2p + (size_t)(b * HN + h) * LQ * DPH;
    bf16x8 a0 = *(const bf16x8*)(k2 + (size_t)(q0 + lm) * 64 + lg * 8);
    bf16x8 a1 = *(const bf16x8*)(k2 + (size_t)(q0 + lm) * 64 + 32 + lg * 8);
#pragma unroll
    for (int s = 0; s < 4; ++s) {
      bf16x8 w0 = *(const bf16x8*)(k1 + (size_t)(k0 + s * 16 + lm) * 64 + lg * 8);
      bf16x8 w1 = *(const bf16x8*)(k1 + (size_t)(k0 + s * 16 + lm) * 64 + 32 + lg * 8);
      f32x4 c = (f32x4){0.f, 0.f, 0.f, 0.f};
      c = mfma16(a0, w0, c);
      c = mfma16(a1, w1, c);
#pragma unroll
      for (int r = 0; r < 4; ++r) hs[s][r] += __expf(c[r]);
    }
  }
  // lane holds 4 consecutive q at fixed k -> one f32x4 store per s-tile
#pragma unroll
  for (int s = 0; s < 4; ++s) {
    f32x4 v;
#pragma unroll
    for (int r = 0; r < 4; ++r) v[r] = 1.0f / hs[s][r];
    *(f32x4*)(invT + ((size_t)b * LQ + k0 + s * 16 + lm) * LQ + q0 + lg * 4) = v;
  }
}

// ---------------------------------------------------------------- ctx 1->2
// c12[l=q, b, m=h*64+d] = sum_k exp(s[q,k])*inv_colsum[k] * v1[k,d]
// 1-D grid 2048, XCD-grouped: group = bh (shares K1/V1T slices), member = q-tile
__global__ __launch_bounds__(256) void ctx12_kernel(const unsigned short* __restrict__ K1p,
                                                    const unsigned short* __restrict__ K2p,
                                                    const unsigned short* __restrict__ V1T,
                                                    const float* __restrict__ inv_colsum,
                                                    unsigned short* __restrict__ c12) {
  int g, m16;
  xcd_group(blockIdx.x, g, m16);
  int bh = g, b = bh >> 4, h = bh & 15;
  int wave = threadIdx.x >> 6, lane = threadIdx.x & 63, lg = lane >> 4, lm = lane & 15;
  int q0 = m16 * 64 + wave * 16;
  const unsigned short* k1 = K1p + (size_t)bh * LQ * DPH;
  const unsigned short* k2 = K2p + (size_t)bh * LQ * DPH;
  const unsigned short* vt = V1T + (size_t)bh * LQ * DPH;
  const float* ics = inv_colsum + (size_t)bh * LQ;

  __shared__ __align__(16) float strip_s[4][16][68];  // wave-private [q16][k64+pad]
  float(*strip)[68] = strip_s[wave];

  bf16x8 a0 = *(const bf16x8*)(k2 + (size_t)(q0 + lm) * 64 + lg * 8);
  bf16x8 a1 = *(const bf16x8*)(k2 + (size_t)(q0 + lm) * 64 + 32 + lg * 8);
  f32x4 acc[4];
#pragma unroll
  for (int s = 0; s < 4; ++s) acc[s] = (f32x4){0.f, 0.f, 0.f, 0.f};

  for (int k0 = 0; k0 < LQ; k0 += 64) {
#pragma unroll
    for (int s = 0; s < 4; ++s) {
      bf16x8 w0 = *(const bf16x8*)(k1 + (size_t)(k0 + s * 16 + lm) * 64 + lg * 8);
      bf16x8 w1 = *(const bf16x8*)(k1 + (size_t)(k0 + s * 16 + lm) * 64 + 32 + lg * 8);
      f32x4 c = (f32x4){0.f, 0.f, 0.f, 0.f};
      c = mfma16(a0, w0, c);
      c = mfma16(a1, w1, c);
      float inv = ics[k0 + s * 16 + lm];
#pragma unroll
      for (int r = 0; r < 4; ++r) strip[lg * 4 + r][s * 16 + lm] = __expf(c[r]) * inv;
    }
    // wave-private LDS round-trip (compiler inserts lgkmcnt waits; no barrier)
#pragma unroll
    for (int kh = 0; kh < 2; ++kh) {
      f32x4 p0 = *(f32x4*)&strip[lm][kh * 32 + lg * 8];
      f32x4 p1 = *(f32x4*)&strip[lm][kh * 32 + lg * 8 + 4];
      bf16x8 a2 = pack8(p0, p1);
#pragma unroll
      for (int s = 0; s < 4; ++s) {
        bf16x8 vb = *(const bf16x8*)(vt + (size_t)(s * 16 + lm) * LQ + k0 + kh * 32 + lg * 8);
        acc[s] = mfma16(a2, vb, acc[s]);
      }
    }
  }
#pragma unroll
  for (int s = 0; s < 4; ++s)
#pragma unroll
    for (int r = 0; r < 4; ++r) {
      int q = q0 + lg * 4 + r;
      c12[((size_t)q * BN + b) * MN + h * 64 + s * 16 + lm] = f2bf(acc[s][r]);
    }
}

// ---------------------------------------------------------------- ctx 2->1
// c21[l=k, b, m=h*64+d] = sum_q exp(s[q,k])*invT[b,k,q] * v2[q,d]
// 1-D grid 2048, XCD-grouped: group = (b, k-tile) so the 16 h-blocks sharing
// the same 256 KB invT tile run consecutively on ONE XCD (L2-resident).
__global__ __launch_bounds__(256) void ctx21_kernel(const unsigned short* __restrict__ K1p,
                                                    const unsigned short* __restrict__ K2p,
                                                    const unsigned short* __restrict__ V2T,
                                                    const float* __restrict__ invT,
                                                    unsigned short* __restrict__ c21) {
  int g, h;
  xcd_group(blockIdx.x, g, h);
  int b = g >> 4, k0idx = g & 15;
  int bh = b * HN + h;
  int wave = threadIdx.x >> 6, lane = threadIdx.x & 63, lg = lane >> 4, lm = lane & 15;
  int k0 = k0idx * 64 + wave * 16;  // wave owns 16 k-rows
  const unsigned short* k1 = K1p + (size_t)bh * LQ * DPH;
  const unsigned short* k2 = K2p + (size_t)bh * LQ * DPH;
  const unsigned short* vt = V2T + (size_t)bh * LQ * DPH;
  const float* ihr = invT + ((size_t)b * LQ + k0 + lm) * LQ;  // this lane's k-row

  __shared__ __align__(16) float strip_s[4][16][68];  // wave-private [k16][q64+pad]
  float(*strip)[68] = strip_s[wave];

  bf16x8 w0 = *(const bf16x8*)(k1 + (size_t)(k0 + lm) * 64 + lg * 8);
  bf16x8 w1 = *(const bf16x8*)(k1 + (size_t)(k0 + lm) * 64 + 32 + lg * 8);
  f32x4 acc[4];
#pragma unroll
  for (int s = 0; s < 4; ++s) acc[s] = (f32x4){0.f, 0.f, 0.f, 0.f};

  for (int q0 = 0; q0 < LQ; q0 += 64) {
#pragma unroll
    for (int qs = 0; qs < 4; ++qs) {
      bf16x8 a0 = *(const bf16x8*)(k2 + (size_t)(q0 + qs * 16 + lm) * 64 + lg * 8);
      bf16x8 a1 = *(const bf16x8*)(k2 + (size_t)(q0 + qs * 16 + lm) * 64 + 32 + lg * 8);
      f32x4 c = (f32x4){0.f, 0.f, 0.f, 0.f};
      c = mfma16(a0, w0, c);
      c = mfma16(a1, w1, c);
      // vectorized normalizer: this lane's k-row, 4 consecutive q
      f32x4 iv = *(const f32x4*)(ihr + q0 + qs * 16 + lg * 4);
#pragma unroll
      for (int r = 0; r < 4; ++r)
        strip[lm][qs * 16 + lg * 4 + r] = __expf(c[r]) * iv[r];  // store transposed [k][q]
    }
#pragma unroll
    for (int qh = 0; qh < 2; ++qh) {
      f32x4 p0 = *(f32x4*)&strip[lm][qh * 32 + lg * 8];
      f32x4 p1 = *(f32x4*)&strip[lm][qh * 32 + lg * 8 + 4];
      bf16x8 a3 = pack8(p0, p1);
#pragma unroll
      for (int s = 0; s < 4; ++s) {
        bf16x8 vb = *(const bf16x8*)(vt + (size_t)(s * 16 + lm) * LQ + q0 + qh * 32 + lg * 8);
        acc[s] = mfma16(a3, vb, acc[s]);
      }
    }
  }
#pragma unroll
  for (int s = 0; s < 4; ++s)
#pragma unroll
    for (int r = 0; r < 4; ++r) {
      int k = k0 + lg * 4 + r;
      c21[((size_t)k * BN + b) * MN + h * 64 + s * 16 + lm] = f2bf(acc[s][r]);
    }
}

// ================================================================ host
extern "C" void kernel_launch(void* const* d_in, const int* in_sizes, int n_in,
                              void* d_out, int out_size, void* d_ws, size_t ws_size,
                              hipStream_t stream) {
  const float* ctx1 = (const float*)d_in[0];
  const float* ctx2 = (const float*)d_in[1];
  const float* Wk1 = (const float*)d_in[2];  const float* bk1 = (const float*)d_in[3];
  const float* Wv1 = (const float*)d_in[4];  const float* bv1 = (const float*)d_in[5];
  const float* Wk2 = (const float*)d_in[6];  const float* bk2 = (const float*)d_in[7];
  const float* Wv2 = (const float*)d_in[8];  const float* bv2 = (const float*)d_in[9];
  const float* Wf12 = (const float*)d_in[10]; const float* bf12 = (const float*)d_in[11];
  const float* Wf21 = (const float*)d_in[12]; const float* bf21 = (const float*)d_in[13];

  char* ws = (char*)d_ws;
  size_t off = 0;
  auto alloc = [&](size_t bytes) {
    void* p = ws + off;
    off += (bytes + 255) & ~(size_t)255;
    return p;
  };
  const size_t KV_BYTES = (size_t)BN * HN * LQ * DPH * 2;  // 16.78 MB

  unsigned short* ctx1b = (unsigned short*)alloc((size_t)LQ * BN * D1N * 2);
  unsigned short* ctx2b = (unsigned short*)alloc((size_t)LQ * BN * D2N * 2);
  unsigned short* wk1b = (unsigned short*)alloc((size_t)MN * D1N * 2);
  unsigned short* wv1b = (unsigned short*)alloc((size_t)MN * D1N * 2);
  unsigned short* wk2b = (unsigned short*)alloc((size_t)MN * D2N * 2);
  unsigned short* wv2b = (unsigned short*)alloc((size_t)MN * D2N * 2);
  unsigned short* wf12b = (unsigned short*)alloc((size_t)MN * MN * 2);
  unsigned short* wf21b = (unsigned short*)alloc((size_t)MN * MN * 2);
  unsigned short* K1buf = (unsigned short*)alloc(KV_BYTES);
  unsigned short* K2buf = (unsigned short*)alloc(KV_BYTES);
  unsigned short* V1T = (unsigned short*)alloc(KV_BYTES);
  unsigned short* V2T = (unsigned short*)alloc(KV_BYTES);
  float* invcs = (float*)alloc((size_t)BN * HN * LQ * 4);
  float* invhs = (float*)alloc((size_t)BN * LQ * LQ * 4);   // transposed [b][k][q]
  unsigned short* c12 = (unsigned short*)alloc(KV_BYTES);
  unsigned short* c21 = (unsigned short*)alloc(KV_BYTES);
  // V1/V2 in [B,H,L,64] layout are only needed until the transpose; alias them
  // onto the c12/c21 buffers (written much later) to save ~34 MB of ws.
  unsigned short* V1tmp = c12;
  unsigned short* V2tmp = c21;

  // ---- phase 1: f32 -> bf16 conversions
  auto cvt = [&](const float* s, unsigned short* d, int n) {
    int n8 = n / 8;
    cvt_kernel<<<(n8 + 255) / 256, 256, 0, stream>>>(s, d, n8);
  };
  cvt(ctx1, ctx1b, LQ * BN * D1N);
  cvt(ctx2, ctx2b, LQ * BN * D2N);
  cvt(Wk1, wk1b, MN * D1N);
  cvt(Wv1, wv1b, MN * D1N);
  cvt(Wk2, wk2b, MN * D2N);
  cvt(Wv2, wv2b, MN * D2N);
  cvt(Wf12, wf12b, MN * MN);
  cvt(Wf21, wf21b, MN * MN);

  // ---- phase 2: projections (rows = 8192)
  dim3 gp(64, 8);
  gemm_kernel<D1N, 0><<<gp, 256, 0, stream>>>(ctx1b, wk1b, bk1, K1buf);
  gemm_kernel<D1N, 0><<<gp, 256, 0, stream>>>(ctx1b, wv1b, bv1, V1tmp);
  gemm_kernel<D2N, 0><<<gp, 256, 0, stream>>>(ctx2b, wk2b, bk2, K2buf);
  gemm_kernel<D2N, 0><<<gp, 256, 0, stream>>>(ctx2b, wv2b, bv2, V2tmp);

  // ---- phase 3: V transposes -> [B,H,64,L]
  dim3 gt(LQ / 64, BN * HN);
  transpose_kernel<<<gt, 256, 0, stream>>>(V1tmp, V1T);
  transpose_kernel<<<gt, 256, 0, stream>>>(V2tmp, V2T);

  // ---- phase 4: normalizer reductions
  col_reduce_kernel<<<2048, 256, 0, stream>>>(K1buf, K2buf, invcs);
  head_reduce_kernel<<<dim3(LQ / 64, LQ / 64, BN), 256, 0, stream>>>(K1buf, K2buf, invhs);

  // ---- phase 5: context passes (recompute scores, weighted AV)
  ctx12_kernel<<<2048, 256, 0, stream>>>(K1buf, K2buf, V1T, invcs, c12);
  ctx21_kernel<<<2048, 256, 0, stream>>>(K1buf, K2buf, V2T, invhs, c21);

  // ---- phase 6: final projections -> f32 d_out (order: context_2_to_1 then context_1_to_2)
  float* out0 = (float*)d_out;                      // [L1, B, M]
  float* out1 = out0 + (size_t)LQ * BN * MN;        // [L2, B, M]
  gemm_kernel<MN, 2><<<gp, 256, 0, stream>>>(c21, wf21b, bf21, out0);
  gemm_kernel<MN, 2><<<gp, 256, 0, stream>>>(c12, wf12b, bf12, out1);
}

// Round 3
// 640.450 us; speedup vs baseline: 1.6802x; 1.6802x over previous
//
#include <hip/hip_runtime.h>
#include <hip/hip_bf16.h>

// Problem constants
constexpr int LQ  = 1024;  // L1 == L2 == 1024
constexpr int BN  = 8;
constexpr int D1N = 512;
constexpr int D2N = 1024;
constexpr int HN  = 16;
constexpr int MN  = 1024;
constexpr int DPH = 64;

typedef __attribute__((ext_vector_type(8)))  short bf16x8;   // 8 bf16 in 4 VGPRs
typedef __attribute__((ext_vector_type(4)))  float f32x4;
typedef __attribute__((ext_vector_type(16))) float f32x16;

__device__ __forceinline__ unsigned short f2bf(float f) {
  unsigned u = __float_as_uint(f);
  u += 0x7FFFu + ((u >> 16) & 1u);   // RNE
  return (unsigned short)(u >> 16);
}
__device__ __forceinline__ float bf2f(unsigned short u) {
  return __uint_as_float(((unsigned)u) << 16);
}

__device__ __forceinline__ f32x4 mfma16(bf16x8 a, bf16x8 b, f32x4 c) {
  return __builtin_amdgcn_mfma_f32_16x16x32_bf16(a, b, c, 0, 0, 0);
}
__device__ __forceinline__ f32x16 mfma32(bf16x8 a, bf16x8 b, f32x16 c) {
  return __builtin_amdgcn_mfma_f32_32x32x16_bf16(a, b, c, 0, 0, 0);
}
__device__ __forceinline__ f32x16 zero16() {
  f32x16 z;
#pragma unroll
  for (int i = 0; i < 16; ++i) z[i] = 0.f;
  return z;
}

__device__ __forceinline__ unsigned cvtpk(float lo, float hi) {
  unsigned r;
  asm("v_cvt_pk_bf16_f32 %0, %1, %2" : "=v"(r) : "v"(lo), "v"(hi));
  return r;
}

// Build PV A-fragment (rows = this lane's C-column, k-elems = C-rows) from 8
// consecutive P regs. C-layout: row=(reg&3)+8*(reg>>2)+4*(lane>>5).
// v_permlane32_swap_b32 D,S: D.hi lanes <-> S.lo lanes.
__device__ __forceinline__ bf16x8 pfrag(const float* p) {
  unsigned x0 = cvtpk(p[0], p[1]), y0 = cvtpk(p[4], p[5]);
  unsigned x1 = cvtpk(p[2], p[3]), y1 = cvtpk(p[6], p[7]);
  asm volatile("v_permlane32_swap_b32 %0, %1" : "+v"(x0), "+v"(y0));
  asm volatile("v_permlane32_swap_b32 %0, %1" : "+v"(x1), "+v"(y1));
  union { unsigned u[4]; bf16x8 v; } r;
  r.u[0] = x0; r.u[1] = x1; r.u[2] = y0; r.u[3] = y1;
  return r.v;
}

__device__ __forceinline__ bf16x8 pack8(f32x4 p0, f32x4 p1) {
  bf16x8 o;
  o[0] = (short)f2bf(p0[0]); o[1] = (short)f2bf(p0[1]);
  o[2] = (short)f2bf(p0[2]); o[3] = (short)f2bf(p0[3]);
  o[4] = (short)f2bf(p1[0]); o[5] = (short)f2bf(p1[1]);
  o[6] = (short)f2bf(p1[2]); o[7] = (short)f2bf(p1[3]);
  return o;
}

// ---------------------------------------------------------------- cvt f32->bf16
__global__ __launch_bounds__(256) void cvt_kernel(const float* __restrict__ src,
                                                  unsigned short* __restrict__ dst,
                                                  int n8) {
  int i = blockIdx.x * blockDim.x + threadIdx.x;
  if (i >= n8) return;
  const f32x4* s = (const f32x4*)src;
  f32x4 x = s[2 * i], y = s[2 * i + 1];
  ((bf16x8*)dst)[i] = pack8(x, y);
}

// ---------------------------------------------------------------- staged GEMM
// A [rows,K] bf16 row-major; W [1024,K] bf16 row-major; C = A @ W^T + bias
// 128x128 tile, BK=32, reg-staged LDS (stride-40 rows, 2-way-max conflicts).
// MODE 0: bf16 to [B,H,L,64]; MODE 2: f32 row-major [rows,1024]
template <int K, int MODE>
__global__ __launch_bounds__(256) void gemm_kernel(const unsigned short* __restrict__ A,
                                                   const unsigned short* __restrict__ W,
                                                   const float* __restrict__ bias,
                                                   void* __restrict__ outp) {
  __shared__ unsigned short As[128 * 40], Bs[128 * 40];
  const int tid = threadIdx.x, wave = tid >> 6, lane = tid & 63;
  const int lg = lane >> 4, lm = lane & 15;
  const int rowb = blockIdx.x * 128, colb = blockIdx.y * 128;
  const int wrow = (wave >> 1) * 64, wcol = (wave & 1) * 64;
  const int sr = tid >> 1, sh = (tid & 1) * 16;
  const unsigned short* Arow = A + (size_t)(rowb + sr) * K + sh;
  const unsigned short* Wrow = W + (size_t)(colb + sr) * K + sh;

  f32x4 acc[4][4];
#pragma unroll
  for (int i = 0; i < 4; ++i)
#pragma unroll
    for (int j = 0; j < 4; ++j) acc[i][j] = (f32x4){0.f, 0.f, 0.f, 0.f};

  for (int kk = 0; kk < K; kk += 32) {
    bf16x8 a0 = *(const bf16x8*)(Arow + kk);
    bf16x8 a1 = *(const bf16x8*)(Arow + kk + 8);
    bf16x8 b0 = *(const bf16x8*)(Wrow + kk);
    bf16x8 b1 = *(const bf16x8*)(Wrow + kk + 8);
    __syncthreads();   // previous iteration's LDS reads done
    *(bf16x8*)&As[sr * 40 + sh] = a0;
    *(bf16x8*)&As[sr * 40 + sh + 8] = a1;
    *(bf16x8*)&Bs[sr * 40 + sh] = b0;
    *(bf16x8*)&Bs[sr * 40 + sh + 8] = b1;
    __syncthreads();
    bf16x8 af[4], wf[4];
#pragma unroll
    for (int i = 0; i < 4; ++i) af[i] = *(const bf16x8*)&As[(wrow + i * 16 + lm) * 40 + lg * 8];
#pragma unroll
    for (int j = 0; j < 4; ++j) wf[j] = *(const bf16x8*)&Bs[(wcol + j * 16 + lm) * 40 + lg * 8];
#pragma unroll
    for (int i = 0; i < 4; ++i)
#pragma unroll
      for (int j = 0; j < 4; ++j) acc[i][j] = mfma16(af[i], wf[j], acc[i][j]);
  }

#pragma unroll
  for (int j = 0; j < 4; ++j) {
    int col = colb + wcol + j * 16 + lm;
    float bs = bias[col];
#pragma unroll
    for (int i = 0; i < 4; ++i) {
#pragma unroll
      for (int r = 0; r < 4; ++r) {
        int row = rowb + wrow + i * 16 + lg * 4 + r;
        float v = acc[i][j][r] + bs;
        if (MODE == 0) {
          int l = row >> 3, bb = row & 7, h = col >> 6, d = col & 63;
          ((unsigned short*)outp)[(((size_t)(bb * HN + h)) * LQ + l) * DPH + d] = f2bf(v);
        } else {
          ((float*)outp)[(size_t)row * MN + col] = v;
        }
      }
    }
  }
}

// ---------------------------------------------------------------- V transpose
// V [BH, L, 64] bf16 -> VT [BH, 64, L]; optional per-source-row scale (1/colsum)
__global__ __launch_bounds__(256) void transpose_kernel(const unsigned short* __restrict__ V,
                                                        unsigned short* __restrict__ VT,
                                                        const float* __restrict__ scale) {
  __shared__ unsigned short t[64][72];
  int bh = blockIdx.y, l0 = blockIdx.x * 64;
  int tid = threadIdx.x;
  int r = tid >> 2, c0 = (tid & 3) * 16;
  const unsigned short* src = V + ((size_t)bh * LQ + l0 + r) * DPH + c0;
  bf16x8 v0 = *(const bf16x8*)(src);
  bf16x8 v1 = *(const bf16x8*)(src + 8);
  if (scale) {
    float sc = scale[(size_t)bh * LQ + l0 + r];
#pragma unroll
    for (int j = 0; j < 8; ++j) {
      v0[j] = (short)f2bf(bf2f((unsigned short)v0[j]) * sc);
      v1[j] = (short)f2bf(bf2f((unsigned short)v1[j]) * sc);
    }
  }
  *(bf16x8*)&t[r][c0] = v0;
  *(bf16x8*)&t[r][c0 + 8] = v1;
  __syncthreads();
  int d = tid >> 2, lc = (tid & 3) * 16;
  bf16x8 o0, o1;
#pragma unroll
  for (int j = 0; j < 8; ++j) {
    o0[j] = (short)t[lc + j][d];
    o1[j] = (short)t[lc + 8 + j][d];
  }
  unsigned short* dst = VT + ((size_t)bh * DPH + d) * LQ + l0 + lc;
  *(bf16x8*)dst = o0;
  *(bf16x8*)(dst + 8) = o1;
}

// ---------------------------------------------------------------- col reduce
// inv_colsum[bh,k] = 1/sum_q exp(s[q,k]).  32x32 MFMA: C[row=q][col=k].
__global__ __launch_bounds__(256) void col_reduce_kernel(const unsigned short* __restrict__ K1p,
                                                         const unsigned short* __restrict__ K2p,
                                                         float* __restrict__ inv_colsum) {
  int bh = blockIdx.y, kb = blockIdx.x * 128;
  int wave = threadIdx.x >> 6, lane = threadIdx.x & 63, l31 = lane & 31, sg = lane >> 5;
  int k0w = kb + wave * 32;
  const unsigned short* k1 = K1p + (size_t)bh * LQ * DPH;
  const unsigned short* k2 = K2p + (size_t)bh * LQ * DPH;
  bf16x8 bk[4];
#pragma unroll
  for (int i = 0; i < 4; ++i)
    bk[i] = *(const bf16x8*)(k1 + (size_t)(k0w + l31) * DPH + i * 16 + sg * 8);
  float tot = 0.f;
  for (int q0 = 0; q0 < LQ; q0 += 32) {
    bf16x8 aq[4];
#pragma unroll
    for (int i = 0; i < 4; ++i)
      aq[i] = *(const bf16x8*)(k2 + (size_t)(q0 + l31) * DPH + i * 16 + sg * 8);
    f32x16 cs = zero16();
#pragma unroll
    for (int i = 0; i < 4; ++i) cs = mfma32(aq[i], bk[i], cs);
#pragma unroll
    for (int r = 0; r < 16; ++r) tot += __expf(cs[r]);
  }
  tot += __shfl_xor(tot, 32);
  if (lane < 32) inv_colsum[(size_t)bh * LQ + k0w + lane] = 1.0f / tot;
}

// ---------------------------------------------------------------- head reduce
// invT[b,k,q] = 1/sum_h exp(s[b,h,q,k]).  C[row=k][col=q] per 32x32 tile.
__global__ __launch_bounds__(256) void head_reduce_kernel(const unsigned short* __restrict__ K1p,
                                                          const unsigned short* __restrict__ K2p,
                                                          float* __restrict__ invT) {
  int b = blockIdx.z, qb = blockIdx.y * 64, kb = blockIdx.x * 64;
  int wave = threadIdx.x >> 6, lane = threadIdx.x & 63, l31 = lane & 31, sg = lane >> 5;
  int qs = (wave & 1) * 32, ks = (wave >> 1) * 32;
  float hs[16];
#pragma unroll
  for (int r = 0; r < 16; ++r) hs[r] = 0.f;

  for (int h = 0; h < HN; ++h) {
    const unsigned short* k1 = K1p + (size_t)(b * HN + h) * LQ * DPH;
    const unsigned short* k2 = K2p + (size_t)(b * HN + h) * LQ * DPH;
    bf16x8 ak[4], bq[4];
#pragma unroll
    for (int i = 0; i < 4; ++i) {
      ak[i] = *(const bf16x8*)(k1 + (size_t)(kb + ks + l31) * DPH + i * 16 + sg * 8);
      bq[i] = *(const bf16x8*)(k2 + (size_t)(qb + qs + l31) * DPH + i * 16 + sg * 8);
    }
    f32x16 cs = zero16();
#pragma unroll
    for (int i = 0; i < 4; ++i) cs = mfma32(ak[i], bq[i], cs);
#pragma unroll
    for (int r = 0; r < 16; ++r) hs[r] += __expf(cs[r]);
  }
#pragma unroll
  for (int r = 0; r < 16; ++r) {
    int k = kb + ks + (r & 3) + 8 * (r >> 2) + 4 * sg;
    invT[((size_t)b * LQ + k) * LQ + qb + qs + l31] = 1.0f / hs[r];
  }
}

// ---------------------------------------------------------------- ctx 1->2
// out[q][d] = sum_k exp(s[q,k]) * V1s[k][d]   (V1s pre-scaled by 1/colsum)
// Score C[row=k][col=q] -> lane's column IS the PV A-frag row. No LDS.
__global__ __launch_bounds__(256) void ctx12_kernel(const unsigned short* __restrict__ K1p,
                                                    const unsigned short* __restrict__ K2p,
                                                    const unsigned short* __restrict__ V1Ts,
                                                    unsigned short* __restrict__ c12) {
  int bh = blockIdx.y, b = bh >> 4, h = bh & 15;
  int wave = threadIdx.x >> 6, lane = threadIdx.x & 63, l31 = lane & 31, sg = lane >> 5;
  int q0 = blockIdx.x * 128 + wave * 32;
  const unsigned short* k1 = K1p + (size_t)bh * LQ * DPH;
  const unsigned short* k2 = K2p + (size_t)bh * LQ * DPH;
  const unsigned short* vt = V1Ts + (size_t)bh * DPH * LQ;

  bf16x8 bq[4];  // K2 rows q (B operand of score), hoisted
#pragma unroll
  for (int i = 0; i < 4; ++i)
    bq[i] = *(const bf16x8*)(k2 + (size_t)(q0 + l31) * DPH + i * 16 + sg * 8);

  f32x16 acc0 = zero16(), acc1 = zero16();
  for (int k0 = 0; k0 < LQ; k0 += 32) {
    bf16x8 ak[4];
#pragma unroll
    for (int i = 0; i < 4; ++i)
      ak[i] = *(const bf16x8*)(k1 + (size_t)(k0 + l31) * DPH + i * 16 + sg * 8);
    f32x16 cs = zero16();
#pragma unroll
    for (int i = 0; i < 4; ++i) cs = mfma32(ak[i], bq[i], cs);  // C[k][q]
    float p[16];
#pragma unroll
    for (int r = 0; r < 16; ++r) p[r] = __expf(cs[r]);
    bf16x8 pa0 = pfrag(p), pa1 = pfrag(p + 8);
    bf16x8 v00 = *(const bf16x8*)(vt + (size_t)l31 * LQ + k0 + sg * 8);
    bf16x8 v01 = *(const bf16x8*)(vt + (size_t)l31 * LQ + k0 + 16 + sg * 8);
    bf16x8 v10 = *(const bf16x8*)(vt + (size_t)(32 + l31) * LQ + k0 + sg * 8);
    bf16x8 v11 = *(const bf16x8*)(vt + (size_t)(32 + l31) * LQ + k0 + 16 + sg * 8);
    acc0 = mfma32(pa0, v00, acc0);
    acc0 = mfma32(pa1, v01, acc0);
    acc1 = mfma32(pa0, v10, acc1);
    acc1 = mfma32(pa1, v11, acc1);
  }
#pragma unroll
  for (int r = 0; r < 16; ++r) {
    int q = q0 + (r & 3) + 8 * (r >> 2) + 4 * sg;
    size_t base = ((size_t)q * BN + b) * MN + h * 64;
    c12[base + l31] = f2bf(acc0[r]);
    c12[base + 32 + l31] = f2bf(acc1[r]);
  }
}

// ---------------------------------------------------------------- ctx 2->1
// out[k][d] = sum_q exp(s[q,k]) * invT[b,k,q] * V2[q,d]
// Score C[row=q][col=k]; invT tile LDS-staged cooperatively (full-line reads,
// XOR-swizzled for conflict-free b128).
__global__ __launch_bounds__(256) void ctx21_kernel(const unsigned short* __restrict__ K1p,
                                                    const unsigned short* __restrict__ K2p,
                                                    const unsigned short* __restrict__ V2T,
                                                    const float* __restrict__ invT,
                                                    unsigned short* __restrict__ c21) {
  __shared__ float ivs[128 * 32];
  int bh = blockIdx.y, b = bh >> 4, h = bh & 15;
  int wave = threadIdx.x >> 6, lane = threadIdx.x & 63, l31 = lane & 31, sg = lane >> 5;
  int kb = blockIdx.x * 128;
  int k0w = kb + wave * 32;
  const unsigned short* k1 = K1p + (size_t)bh * LQ * DPH;
  const unsigned short* k2 = K2p + (size_t)bh * LQ * DPH;
  const unsigned short* vt = V2T + (size_t)bh * DPH * LQ;
  const float* ivbase = invT + (size_t)b * LQ * LQ;

  bf16x8 bk[4];  // K1 rows k (B operand of score), hoisted
#pragma unroll
  for (int i = 0; i < 4; ++i)
    bk[i] = *(const bf16x8*)(k1 + (size_t)(k0w + l31) * DPH + i * 16 + sg * 8);

  const int srsub = lane >> 3, sq = (lane & 7) * 4;
  const int myrow = wave * 32 + l31;
  f32x16 acc0 = zero16(), acc1 = zero16();

  for (int q0 = 0; q0 < LQ; q0 += 32) {
    __syncthreads();  // previous iteration's LDS reads done
#pragma unroll
    for (int s = 0; s < 4; ++s) {
      int row = wave * 32 + s * 8 + srsub;
      f32x4 d = *(const f32x4*)(ivbase + (size_t)(kb + row) * LQ + q0 + sq);
      *(f32x4*)&ivs[row * 32 + (sq ^ ((row & 7) << 2))] = d;
    }
    __syncthreads();
    bf16x8 aq[4];
#pragma unroll
    for (int i = 0; i < 4; ++i)
      aq[i] = *(const bf16x8*)(k2 + (size_t)(q0 + l31) * DPH + i * 16 + sg * 8);
    f32x16 cs = zero16();
#pragma unroll
    for (int i = 0; i < 4; ++i) cs = mfma32(aq[i], bk[i], cs);  // C[q][k]
    float p[16];
#pragma unroll
    for (int t = 0; t < 4; ++t) {
      int qq = 8 * t + 4 * sg;
      f32x4 iv = *(const f32x4*)&ivs[myrow * 32 + (qq ^ ((myrow & 7) << 2))];
#pragma unroll
      for (int j = 0; j < 4; ++j) p[t * 4 + j] = __expf(cs[t * 4 + j]) * iv[j];
    }
    bf16x8 pa0 = pfrag(p), pa1 = pfrag(p + 8);
    bf16x8 v00 = *(const bf16x8*)(vt + (size_t)l31 * LQ + q0 + sg * 8);
    bf16x8 v01 = *(const bf16x8*)(vt + (size_t)l31 * LQ + q0 + 16 + sg * 8);
    bf16x8 v10 = *(const bf16x8*)(vt + (size_t)(32 + l31) * LQ + q0 + sg * 8);
    bf16x8 v11 = *(const bf16x8*)(vt + (size_t)(32 + l31) * LQ + q0 + 16 + sg * 8);
    acc0 = mfma32(pa0, v00, acc0);
    acc0 = mfma32(pa1, v01, acc0);
    acc1 = mfma32(pa0, v10, acc1);
    acc1 = mfma32(pa1, v11, acc1);
  }
#pragma unroll
  for (int r = 0; r < 16; ++r) {
    int k = k0w + (r & 3) + 8 * (r >> 2) + 4 * sg;
    size_t base = ((size_t)k * BN + b) * MN + h * 64;
    c21[base + l31] = f2bf(acc0[r]);
    c21[base + 32 + l31] = f2bf(acc1[r]);
  }
}

// ================================================================ host
extern "C" void kernel_launch(void* const* d_in, const int* in_sizes, int n_in,
                              void* d_out, int out_size, void* d_ws, size_t ws_size,
                              hipStream_t stream) {
  const float* ctx1 = (const float*)d_in[0];
  const float* ctx2 = (const float*)d_in[1];
  const float* Wk1 = (const float*)d_in[2];  const float* bk1 = (const float*)d_in[3];
  const float* Wv1 = (const float*)d_in[4];  const float* bv1 = (const float*)d_in[5];
  const float* Wk2 = (const float*)d_in[6];  const float* bk2 = (const float*)d_in[7];
  const float* Wv2 = (const float*)d_in[8];  const float* bv2 = (const float*)d_in[9];
  const float* Wf12 = (const float*)d_in[10]; const float* bf12 = (const float*)d_in[11];
  const float* Wf21 = (const float*)d_in[12]; const float* bf21 = (const float*)d_in[13];

  char* ws = (char*)d_ws;
  size_t off = 0;
  auto alloc = [&](size_t bytes) {
    void* p = ws + off;
    off += (bytes + 255) & ~(size_t)255;
    return p;
  };
  const size_t KV_BYTES = (size_t)BN * HN * LQ * DPH * 2;  // 16.78 MB

  unsigned short* ctx1b = (unsigned short*)alloc((size_t)LQ * BN * D1N * 2);
  unsigned short* ctx2b = (unsigned short*)alloc((size_t)LQ * BN * D2N * 2);
  unsigned short* wk1b = (unsigned short*)alloc((size_t)MN * D1N * 2);
  unsigned short* wv1b = (unsigned short*)alloc((size_t)MN * D1N * 2);
  unsigned short* wk2b = (unsigned short*)alloc((size_t)MN * D2N * 2);
  unsigned short* wv2b = (unsigned short*)alloc((size_t)MN * D2N * 2);
  unsigned short* wf12b = (unsigned short*)alloc((size_t)MN * MN * 2);
  unsigned short* wf21b = (unsigned short*)alloc((size_t)MN * MN * 2);
  unsigned short* K1buf = (unsigned short*)alloc(KV_BYTES);
  unsigned short* K2buf = (unsigned short*)alloc(KV_BYTES);
  unsigned short* V1T = (unsigned short*)alloc(KV_BYTES);   // scaled by 1/colsum
  unsigned short* V2T = (unsigned short*)alloc(KV_BYTES);
  float* invcs = (float*)alloc((size_t)BN * HN * LQ * 4);
  float* invhs = (float*)alloc((size_t)BN * LQ * LQ * 4);   // [b][k][q]
  unsigned short* c12 = (unsigned short*)alloc(KV_BYTES);
  unsigned short* c21 = (unsigned short*)alloc(KV_BYTES);
  unsigned short* V1tmp = c12;  // alias: dead before c12 written
  unsigned short* V2tmp = c21;

  // ---- phase 1: f32 -> bf16 conversions
  auto cvt = [&](const float* s, unsigned short* d, int n) {
    int n8 = n / 8;
    cvt_kernel<<<(n8 + 255) / 256, 256, 0, stream>>>(s, d, n8);
  };
  cvt(ctx1, ctx1b, LQ * BN * D1N);
  cvt(ctx2, ctx2b, LQ * BN * D2N);
  cvt(Wk1, wk1b, MN * D1N);
  cvt(Wv1, wv1b, MN * D1N);
  cvt(Wk2, wk2b, MN * D2N);
  cvt(Wv2, wv2b, MN * D2N);
  cvt(Wf12, wf12b, MN * MN);
  cvt(Wf21, wf21b, MN * MN);

  // ---- phase 2: projections (rows = 8192)
  dim3 gp(64, 8);
  gemm_kernel<D1N, 0><<<gp, 256, 0, stream>>>(ctx1b, wk1b, bk1, K1buf);
  gemm_kernel<D1N, 0><<<gp, 256, 0, stream>>>(ctx1b, wv1b, bv1, V1tmp);
  gemm_kernel<D2N, 0><<<gp, 256, 0, stream>>>(ctx2b, wk2b, bk2, K2buf);
  gemm_kernel<D2N, 0><<<gp, 256, 0, stream>>>(ctx2b, wv2b, bv2, V2tmp);

  // ---- phase 3: colsum reduction, then V transposes (V1 scaled by 1/colsum)
  col_reduce_kernel<<<dim3(LQ / 128, BN * HN), 256, 0, stream>>>(K1buf, K2buf, invcs);
  dim3 gt(LQ / 64, BN * HN);
  transpose_kernel<<<gt, 256, 0, stream>>>(V1tmp, V1T, invcs);
  transpose_kernel<<<gt, 256, 0, stream>>>(V2tmp, V2T, nullptr);

  // ---- phase 4: head-sum reduction -> invT [b][k][q]
  head_reduce_kernel<<<dim3(LQ / 64, LQ / 64, BN), 256, 0, stream>>>(K1buf, K2buf, invhs);

  // ---- phase 5: context passes (in-register P, swapped-operand scores)
  ctx12_kernel<<<dim3(LQ / 128, BN * HN), 256, 0, stream>>>(K1buf, K2buf, V1T, c12);
  ctx21_kernel<<<dim3(LQ / 128, BN * HN), 256, 0, stream>>>(K1buf, K2buf, V2T, invhs, c21);

  // ---- phase 6: final projections -> f32 d_out (context_2_to_1 first)
  float* out0 = (float*)d_out;                 // [L1, B, M]
  float* out1 = out0 + (size_t)LQ * BN * MN;   // [L2, B, M]
  gemm_kernel<MN, 2><<<gp, 256, 0, stream>>>(c21, wf21b, bf21, out0);
  gemm_kernel<MN, 2><<<gp, 256, 0, stream>>>(c12, wf12b, bf12, out1);
}